// Round 24
// baseline (61.318 us; speedup 1.0000x reference)
//
#include <hip/hip_runtime.h>
#include <hip/hip_bf16.h>

typedef __attribute__((ext_vector_type(8))) short bf16x8;
typedef __attribute__((ext_vector_type(16))) float f32x16;

__device__ __forceinline__ ushort f2bf(float x) {
  unsigned u = __float_as_uint(x);
  u = (u + 0x7FFFu + ((u >> 16) & 1u)) >> 16;
  return (ushort)u;
}

// Pack K (f32 [256][1024]) into 32x32x16-MFMA B-fragment order:
// chunk c = (otile 0..31, ks16 0..15, lane 0..63); chunk holds 8 bf16:
//   o = otile*32 + (lane&31), k = ks16*16 + (lane>>5)*8 + e
__global__ void WV_kconv(const float* __restrict__ K, ushort* __restrict__ KtQ) {
  int c = blockIdx.x * 256 + threadIdx.x;  // 0..32767
  int otile = c >> 10, ks16 = (c >> 6) & 15, lane = c & 63;
  int o = otile * 32 + (lane & 31);
  int kb = ks16 * 16 + (lane >> 5) * 8;
  bf16x8 w;
  #pragma unroll
  for (int e = 0; e < 8; ++e)
    w[e] = (short)f2bf(K[(size_t)(kb + e) * 1024 + o]);
  *reinterpret_cast<bf16x8*>(KtQ + (size_t)c * 8) = w;
}

// Block (b,h): h = i-QUARTER (64 rows) -> 32 KB LDS -> 2 blocks/CU,
// 4 waves/SIMD. 8 waves; wave owns o-strip of 128 (2 og x 2 ot x 32).
// R24: 32x32x16 MFMA rewrite. Per og: 32 MFMA (vs 128 16x16), -17%
// MFMA-pipe, 4x fewer issue slots; epilogue needs ONE shfl_xor(32) per
// o-tile (C/D: col=lane&31, row=(reg&3)+8*(reg>>2)+4*(lane>>5)).
// acc = 2x2 f32x16 = 64 regs; copy-free B ping-pong (R23 pattern).
// LDS swizzle (m&15)<<5: A-read = 32 rows x 2 slots -> 32 distinct
// slots, 2 lanes/slot = conflict-free.
__global__ __launch_bounds__(512, 2) void WV_main(
    const float* __restrict__ A, const ushort* __restrict__ KtQ,
    float* __restrict__ out) {
  __shared__ short As[64 * 256];  // 32 KB
  const int bh = blockIdx.x;
  const int b = bh >> 2, h = bh & 3;
  const float* Ah = A + (size_t)b * 65536 + (size_t)h * 16384;
  const int t = threadIdx.x;

  // ---- stage 64 rows: fp32 -> bf16, swizzle byte ^= (row&15)<<5 ----
  #pragma unroll 1
  for (int it = 0; it < 4; ++it) {
    int c = it * 512 + t;  // chunk of 8 floats
    int m = c >> 5;        // local row 0..63
    int s = c & 31;        // 16B slot within row
    const float4* p = reinterpret_cast<const float4*>(Ah) + c * 2;
    float4 v0 = p[0], v1 = p[1];
    bf16x8 w;
    w[0] = (short)f2bf(v0.x); w[1] = (short)f2bf(v0.y);
    w[2] = (short)f2bf(v0.z); w[3] = (short)f2bf(v0.w);
    w[4] = (short)f2bf(v1.x); w[5] = (short)f2bf(v1.y);
    w[6] = (short)f2bf(v1.z); w[7] = (short)f2bf(v1.w);
    int byteoff = m * 512 + ((s * 16) ^ ((m & 15) << 5));
    *reinterpret_cast<bf16x8*>(reinterpret_cast<char*>(As) + byteoff) = w;
  }
  __syncthreads();

  const int wave = t >> 6, lane = t & 63;
  const int lo32 = lane & 31;  // row (A) / col (B,D) within 32-tile
  const int hi1 = lane >> 5;   // 0..1: k-group (A,B) / row-group (D)
  const ushort* KtL = KtQ + lane * 8;  // per-lane base

  #pragma unroll 1
  for (int og = 0; og < 2; ++og) {
    const int otb = wave * 4 + og * 2;  // otile32 base (wave-uniform)

    f32x16 acc[2][2];
    #pragma unroll
    for (int a1 = 0; a1 < 2; ++a1)
      #pragma unroll
      for (int a2 = 0; a2 < 2; ++a2)
        acc[a1][a2] = (f32x16)(0.f);

    bf16x8 B0[2], B1[2];  // scoped to og, copy-free ping-pong
    #pragma unroll
    for (int ot = 0; ot < 2; ++ot)
      B0[ot] = *reinterpret_cast<const bf16x8*>(
          KtL + __builtin_amdgcn_readfirstlane(((otb + ot) * 16 + 0) * 512));

    #pragma unroll 1
    for (int kp = 0; kp < 8; ++kp) {
      const int ks0 = kp * 2, ks1 = kp * 2 + 1;
      // load odd-half B
      #pragma unroll
      for (int ot = 0; ot < 2; ++ot)
        B1[ot] = *reinterpret_cast<const bf16x8*>(
            KtL + __builtin_amdgcn_readfirstlane(((otb + ot) * 16 + ks1) * 512));
      // compute even half from B0
      __builtin_amdgcn_s_setprio(1);
      #pragma unroll
      for (int itl = 0; itl < 2; ++itl) {
        int m = itl * 32 + lo32;
        int byteoff = m * 512 + ((ks0 * 32 + hi1 * 16) ^ ((m & 15) << 5));
        bf16x8 Af = *reinterpret_cast<const bf16x8*>(
            reinterpret_cast<char*>(As) + byteoff);
        #pragma unroll
        for (int ot = 0; ot < 2; ++ot)
          acc[itl][ot] = __builtin_amdgcn_mfma_f32_32x32x16_bf16(
              Af, B0[ot], acc[itl][ot], 0, 0, 0);
      }
      __builtin_amdgcn_s_setprio(0);
      // reload even-half B for next pair (dead at kp==7)
      if (kp < 7) {
        #pragma unroll
        for (int ot = 0; ot < 2; ++ot)
          B0[ot] = *reinterpret_cast<const bf16x8*>(
              KtL + __builtin_amdgcn_readfirstlane(((otb + ot) * 16 + ks0 + 2) * 512));
      }
      // compute odd half from B1
      __builtin_amdgcn_s_setprio(1);
      #pragma unroll
      for (int itl = 0; itl < 2; ++itl) {
        int m = itl * 32 + lo32;
        int byteoff = m * 512 + ((ks1 * 32 + hi1 * 16) ^ ((m & 15) << 5));
        bf16x8 Af = *reinterpret_cast<const bf16x8*>(
            reinterpret_cast<char*>(As) + byteoff);
        #pragma unroll
        for (int ot = 0; ot < 2; ++ot)
          acc[itl][ot] = __builtin_amdgcn_mfma_f32_32x32x16_bf16(
              Af, B1[ot], acc[itl][ot], 0, 0, 0);
      }
      __builtin_amdgcn_s_setprio(0);
    }

    // epilogue: out[b,o] += sum_i K[i,o]*C[i,o].
    // Lane holds col o=(otb+ot)*32+lo32, rows i = h*64 + itl*32 +
    // (reg&3) + 8*(reg>>2) + 4*hi1. Weights from KtQ: chunk
    // (otb+ot, kse=h*4+itl*2+(rq>>1)), lanepos=((rq&1)<<5)|lo32,
    // elems 4*hi1+j  (== i for reg=rq*4+j, verified algebra).
    #pragma unroll
    for (int ot = 0; ot < 2; ++ot) {
      float s = 0.f;
      #pragma unroll
      for (int itl = 0; itl < 2; ++itl) {
        #pragma unroll
        for (int rq = 0; rq < 4; ++rq) {
          const int kse = h * 4 + itl * 2 + (rq >> 1);
          const ushort* wp = KtQ +
              ((size_t)((otb + ot) * 16 + kse) * 64 + ((rq & 1) << 5) + lo32) * 8
              + 4 * hi1;
          ushort4 wv = *reinterpret_cast<const ushort4*>(wp);
          const int rb = rq * 4;
          s += __uint_as_float((unsigned)wv.x << 16) * acc[itl][ot][rb + 0]
             + __uint_as_float((unsigned)wv.y << 16) * acc[itl][ot][rb + 1]
             + __uint_as_float((unsigned)wv.z << 16) * acc[itl][ot][rb + 2]
             + __uint_as_float((unsigned)wv.w << 16) * acc[itl][ot][rb + 3];
        }
      }
      s += __shfl_xor(s, 32);
      if (lane < 32)
        atomicAdd(&out[(size_t)b * 1024 + (otb + ot) * 32 + lane], s);
    }
  }
}

extern "C" void kernel_launch(void* const* d_in, const int* in_sizes, int n_in,
                              void* d_out, int out_size, void* d_ws, size_t ws_size,
                              hipStream_t stream) {
  const float* A = (const float*)d_in[0];   // (256,256,256) f32
  const float* K = (const float*)d_in[1];   // (256,1024)   f32
  float* out = (float*)d_out;               // (256,1024)   f32
  ushort* KtQ = (ushort*)d_ws;              // packed (32,16,64,8) bf16
  hipMemsetAsync(d_out, 0, (size_t)out_size * sizeof(float), stream);
  WV_kconv<<<128, 256, 0, stream>>>(K, KtQ);
  WV_main<<<1024, 512, 0, stream>>>(A, KtQ, out);
}

// Round 28
// 54.605 us; speedup vs baseline: 1.1229x; 1.1229x over previous
//
#include <hip/hip_runtime.h>
#include <hip/hip_bf16.h>

typedef __attribute__((ext_vector_type(8))) short bf16x8;
typedef __attribute__((ext_vector_type(4))) float f32x4;

__device__ __forceinline__ ushort f2bf(float x) {
  unsigned u = __float_as_uint(x);
  u = (u + 0x7FFFu + ((u >> 16) & 1u)) >> 16;
  return (ushort)u;
}

// Pack K (f32 [256][1024]) into MFMA-fragment order:
// chunk c = (otile 0..63, ks 0..7, lane 0..63); chunk holds 8 bf16:
//   o = otile*16 + (lane&15), k = ks*32 + (lane>>4)*8 + e
__global__ void WV_kconv(const float* __restrict__ K, ushort* __restrict__ KtP) {
  int c = blockIdx.x * 256 + threadIdx.x;  // 0..32767
  int otile = c >> 9, ks = (c >> 6) & 7, lane = c & 63;
  int o = otile * 16 + (lane & 15);
  int kb = ks * 32 + (lane >> 4) * 8;
  bf16x8 w;
  #pragma unroll
  for (int e = 0; e < 8; ++e)
    w[e] = (short)f2bf(K[(size_t)(kb + e) * 1024 + o]);
  *reinterpret_cast<bf16x8*>(KtP + (size_t)c * 8) = w;
}

// FINAL (R23 best-measured, 54.5 us = ~630 TF effective).
// Block (b,h): h = i-QUARTER (64 rows) -> 32 KB LDS -> 2 blocks/CU,
// 4 waves/SIMD (64 arch + 64 acc = 128 regs exactly at the wave-capacity
// boundary). 8 waves; wave owns o-strip of 128 (2 og x 4 ot x 16).
// Copy-free unroll-2 B ping-pong; B-load addr = per-lane base (KtL) +
// wave-uniform SGPR offset (readfirstlane). Structural plateau: MFMA /
// L2-B / VALU / LDS pipes balanced at ~15 us each; any deeper ILP
// crosses the 128-reg wall and halves occupancy (R3/R8/R14/R20/R22).
__global__ __launch_bounds__(512, 2) void WV_main(
    const float* __restrict__ A, const ushort* __restrict__ KtP,
    float* __restrict__ out) {
  __shared__ short As[64 * 256];  // 32 KB
  const int bh = blockIdx.x;
  const int b = bh >> 2, h = bh & 3;
  const float* Ah = A + (size_t)b * 65536 + (size_t)h * 16384;
  const int t = threadIdx.x;

  // ---- stage 64 rows: fp32 -> bf16, swizzle byte ^= (row&7)<<6 ----
  #pragma unroll 1
  for (int it = 0; it < 4; ++it) {
    int c = it * 512 + t;  // chunk of 8 floats
    int m = c >> 5;        // local row 0..63
    int s = c & 31;        // 16B slot within row
    const float4* p = reinterpret_cast<const float4*>(Ah) + c * 2;
    float4 v0 = p[0], v1 = p[1];
    bf16x8 w;
    w[0] = (short)f2bf(v0.x); w[1] = (short)f2bf(v0.y);
    w[2] = (short)f2bf(v0.z); w[3] = (short)f2bf(v0.w);
    w[4] = (short)f2bf(v1.x); w[5] = (short)f2bf(v1.y);
    w[6] = (short)f2bf(v1.z); w[7] = (short)f2bf(v1.w);
    int byteoff = m * 512 + ((s * 16) ^ ((m & 7) << 6));
    *reinterpret_cast<bf16x8*>(reinterpret_cast<char*>(As) + byteoff) = w;
  }
  __syncthreads();

  const int wave = t >> 6, lane = t & 63;
  const int lo = lane & 15;   // col within tile (B,D) / row (A)
  const int hi = lane >> 4;   // 0..3
  const ushort* KtL = KtP + lane * 8;  // per-lane base, computed once

  #pragma unroll 1
  for (int og = 0; og < 2; ++og) {
    float oseg[4] = {0.f, 0.f, 0.f, 0.f};
    const int otb = wave * 8 + og * 4;  // o-tile base (wave-uniform)

    f32x4 acc[4][4];
    #pragma unroll
    for (int a1 = 0; a1 < 4; ++a1)
      #pragma unroll
      for (int a2 = 0; a2 < 4; ++a2)
        acc[a1][a2] = (f32x4){0.f, 0.f, 0.f, 0.f};

    bf16x8 B0[4], B1[4];  // scoped to og
    #pragma unroll
    for (int ot = 0; ot < 4; ++ot)
      B0[ot] = *reinterpret_cast<const bf16x8*>(
          KtL + __builtin_amdgcn_readfirstlane((otb + ot) * 4096));

    #pragma unroll 1
    for (int kp = 0; kp < 4; ++kp) {
      const int ks0 = kp * 2, ks1 = kp * 2 + 1;
      // load odd-half B (SGPR chunk offset + per-lane base)
      #pragma unroll
      for (int ot = 0; ot < 4; ++ot)
        B1[ot] = *reinterpret_cast<const bf16x8*>(
            KtL + __builtin_amdgcn_readfirstlane((otb + ot) * 4096 + ks1 * 512));
      // compute even half from B0
      __builtin_amdgcn_s_setprio(1);
      #pragma unroll
      for (int itl = 0; itl < 4; ++itl) {
        int m = itl * 16 + lo;
        int byteoff = m * 512 + ((ks0 * 64 + hi * 16) ^ ((m & 7) << 6));
        bf16x8 Af = *reinterpret_cast<const bf16x8*>(
            reinterpret_cast<char*>(As) + byteoff);
        #pragma unroll
        for (int ot = 0; ot < 4; ++ot)
          acc[itl][ot] = __builtin_amdgcn_mfma_f32_16x16x32_bf16(
              Af, B0[ot], acc[itl][ot], 0, 0, 0);
      }
      __builtin_amdgcn_s_setprio(0);
      // reload even-half B for next pair (dead at kp==3)
      if (kp < 3) {
        #pragma unroll
        for (int ot = 0; ot < 4; ++ot)
          B0[ot] = *reinterpret_cast<const bf16x8*>(
              KtL + __builtin_amdgcn_readfirstlane((otb + ot) * 4096 +
                                                   (ks0 + 2) * 512));
      }
      // compute odd half from B1
      __builtin_amdgcn_s_setprio(1);
      #pragma unroll
      for (int itl = 0; itl < 4; ++itl) {
        int m = itl * 16 + lo;
        int byteoff = m * 512 + ((ks1 * 64 + hi * 16) ^ ((m & 7) << 6));
        bf16x8 Af = *reinterpret_cast<const bf16x8*>(
            reinterpret_cast<char*>(As) + byteoff);
        #pragma unroll
        for (int ot = 0; ot < 4; ++ot)
          acc[itl][ot] = __builtin_amdgcn_mfma_f32_16x16x32_bf16(
              Af, B1[ot], acc[itl][ot], 0, 0, 0);
      }
      __builtin_amdgcn_s_setprio(0);
    }

    // epilogue: weights K[i0..i0+3][o(lane)] from KtP packed layout.
    // i0 = h*64+itl*16+hi*4 = kse*32+g*8+e with kse = h*2+(itl>>1),
    // g = (itl&1)*2+(hi>>1), e = (hi&1)*4.
    #pragma unroll
    for (int itl = 0; itl < 4; ++itl) {
      const int kse = h * 2 + (itl >> 1);
      const int g = (itl & 1) * 2 + (hi >> 1);
      const int e = (hi & 1) * 4;
      #pragma unroll
      for (int ot = 0; ot < 4; ++ot) {
        const ushort* wp = KtP +
            ((size_t)((otb + ot) * 8 + kse) * 64 + lo + g * 16) * 8 + e;
        ushort4 wv = *reinterpret_cast<const ushort4*>(wp);
        f32x4 a = acc[itl][ot];
        float s = __uint_as_float((unsigned)wv.x << 16) * a[0]
                + __uint_as_float((unsigned)wv.y << 16) * a[1]
                + __uint_as_float((unsigned)wv.z << 16) * a[2]
                + __uint_as_float((unsigned)wv.w << 16) * a[3];
        s += __shfl_xor(s, 16);
        s += __shfl_xor(s, 32);
        oseg[ot] += s;
      }
    }

    if (lane < 16) {
      #pragma unroll
      for (int ot = 0; ot < 4; ++ot)
        atomicAdd(&out[(size_t)b * 1024 + (otb + ot) * 16 + lane], oseg[ot]);
    }
  }
}

extern "C" void kernel_launch(void* const* d_in, const int* in_sizes, int n_in,
                              void* d_out, int out_size, void* d_ws, size_t ws_size,
                              hipStream_t stream) {
  const float* A = (const float*)d_in[0];   // (256,256,256) f32
  const float* K = (const float*)d_in[1];   // (256,1024)   f32
  float* out = (float*)d_out;               // (256,1024)   f32
  ushort* KtP = (ushort*)d_ws;              // packed (64,8,64,8) bf16
  hipMemsetAsync(d_out, 0, (size_t)out_size * sizeof(float), stream);
  WV_kconv<<<128, 256, 0, stream>>>(K, KtP);
  WV_main<<<1024, 512, 0, stream>>>(A, KtP, out);
}